// Round 2
// baseline (2060.058 us; speedup 1.0000x reference)
//
#include <hip/hip_runtime.h>

using u8  = unsigned char;
using u16 = unsigned short;
using u32 = unsigned int;

typedef __attribute__((ext_vector_type(8))) short bf16x8;
typedef __attribute__((ext_vector_type(4))) float f32x4;
typedef __attribute__((ext_vector_type(4))) u32  u32x4;
typedef __attribute__((ext_vector_type(4))) u16  u16x4;

__device__ __forceinline__ u16 f2bf(float f) {
  u32 u = __builtin_bit_cast(u32, f);
  u = (u + 0x7FFFu + ((u >> 16) & 1u)) >> 16;
  return (u16)u;
}

// ---------------- mask dtype probe ----------------
// flag = 0 -> byte mask (numpy bool), 1 -> 4-byte mask (int32 or fp32); in
// both 4-byte cases "nonzero word == masked" is correct.
__global__ void probe_mask(const u32* __restrict__ m, u32* __restrict__ flag) {
  __shared__ int bad;
  if (threadIdx.x == 0) bad = 0;
  __syncthreads();
  int lb = 0;
  for (int i = threadIdx.x; i < 16384; i += 256) {
    u32 v = m[i];
    if (v > 1u && v != 0x3F800000u) lb = 1;
  }
  if (lb) atomicOr(&bad, 1);
  __syncthreads();
  if (threadIdx.x == 0) *flag = bad ? 0u : 1u;
}

// ---------------- GEMM: C = A[M,K] * B[N,K]^T (+epilogue) ----------------
// MODE 0: qh   -> bf16 [B,H,L,64]
// MODE 1: kh'  -> bf16 [B,H,L,64], += w_es[h,l,d]
// MODE 2: vt   -> bf16 [B,H,64,L]   (V transposed for PV B-operand reads)
// MODE 3: fc   -> fp32 X[m,n] = acc + fc_b[n] + residual[m,n]
template <int MODE>
__global__ __launch_bounds__(256) void gemm_bt(
    const float* __restrict__ Af, const u16* __restrict__ Ab,
    const float* __restrict__ Bf, const float* __restrict__ bias,
    const float* __restrict__ wes, const float* __restrict__ resid,
    u16* __restrict__ outb, float* __restrict__ outf)
{
  __shared__ char lds[32768];
  char* As = lds;
  char* Bs = lds + 16384;
  const int t = threadIdx.x;
  const int m0 = (blockIdx.x >> 3) << 7;   // M/128 = 64 blocks
  const int n0 = (blockIdx.x & 7) << 7;    // N/128 = 8 blocks
  const int lane = t & 63, w = t >> 6;
  const int lr = lane & 15, lg = lane >> 4;
  const int wr = w >> 1, wc = w & 1;

  f32x4 acc[4][4] = {};

  for (int kt = 0; kt < 16; ++kt) {
    const int k0 = kt << 6;
    __syncthreads();
    if constexpr (MODE == 3) {
      #pragma unroll
      for (int j = 0; j < 4; ++j) {
        int f = j * 256 + t, r = f >> 3, c = f & 7;
        u32x4 v = *(const u32x4*)(Ab + (size_t)(m0 + r) * 1024 + k0 + c * 8);
        *(u32x4*)(As + r * 128 + ((c ^ (r & 7)) << 4)) = v;
      }
    } else {
      #pragma unroll
      for (int j = 0; j < 8; ++j) {
        int f = j * 256 + t, r = f >> 4, c = f & 15;
        float4 v = *(const float4*)(Af + (size_t)(m0 + r) * 1024 + k0 + c * 4);
        u16x4 p = { f2bf(v.x), f2bf(v.y), f2bf(v.z), f2bf(v.w) };
        *(u16x4*)(As + r * 128 + (((c >> 1) ^ (r & 7)) << 4) + ((c & 1) << 3)) = p;
      }
    }
    #pragma unroll
    for (int j = 0; j < 8; ++j) {
      int f = j * 256 + t, r = f >> 4, c = f & 15;
      float4 v = *(const float4*)(Bf + (size_t)(n0 + r) * 1024 + k0 + c * 4);
      u16x4 p = { f2bf(v.x), f2bf(v.y), f2bf(v.z), f2bf(v.w) };
      *(u16x4*)(Bs + r * 128 + (((c >> 1) ^ (r & 7)) << 4) + ((c & 1) << 3)) = p;
    }
    __syncthreads();
    #pragma unroll
    for (int ks = 0; ks < 2; ++ks) {
      bf16x8 a[4], bb[4];
      #pragma unroll
      for (int mf = 0; mf < 4; ++mf) {
        int row = wr * 64 + mf * 16 + lr;
        a[mf] = *(const bf16x8*)(As + row * 128 + (((ks * 4 + lg) ^ (row & 7)) << 4));
      }
      #pragma unroll
      for (int nf = 0; nf < 4; ++nf) {
        int row = wc * 64 + nf * 16 + lr;
        bb[nf] = *(const bf16x8*)(Bs + row * 128 + (((ks * 4 + lg) ^ (row & 7)) << 4));
      }
      #pragma unroll
      for (int mf = 0; mf < 4; ++mf)
        #pragma unroll
        for (int nf = 0; nf < 4; ++nf)
          acc[mf][nf] = __builtin_amdgcn_mfma_f32_16x16x32_bf16(a[mf], bb[nf], acc[mf][nf], 0, 0, 0);
    }
  }

  #pragma unroll
  for (int mf = 0; mf < 4; ++mf)
    #pragma unroll
    for (int nf = 0; nf < 4; ++nf)
      #pragma unroll
      for (int i = 0; i < 4; ++i) {
        int mg = m0 + wr * 64 + mf * 16 + lg * 4 + i;
        int ng = n0 + wc * 64 + nf * 16 + lr;
        float v = acc[mf][nf][i] + bias[ng];
        if constexpr (MODE == 1)
          v += wes[((size_t)(ng >> 6) * 1024 + (mg & 1023)) * 64 + (ng & 63)];
        if constexpr (MODE <= 1) {
          outb[((size_t)((mg >> 10) * 16 + (ng >> 6)) * 1024 + (mg & 1023)) * 64 + (ng & 63)] = f2bf(v);
        } else if constexpr (MODE == 2) {
          outb[((size_t)((mg >> 10) * 16 + (ng >> 6)) * 64 + (ng & 63)) * 1024 + (mg & 1023)] = f2bf(v);
        } else {
          outf[(size_t)mg * 1024 + ng] = v + resid[(size_t)mg * 1024 + ng];
        }
      }
}

// ---------------- attention ----------------
// grid = (B*H*8); block = 256 (4 waves, 32 q-rows each). Two passes:
// pass1 exact softmax stats; pass2 recompute S, write normalized P (fp32
// attn output + bf16 Ps in LDS), accumulate O = P*V.
__global__ __launch_bounds__(256) void attn_kernel(
    const u16* __restrict__ qh, const u16* __restrict__ khp, const u16* __restrict__ vt,
    const void* __restrict__ maskp, const u32* __restrict__ fmtp,
    float* __restrict__ attn_out, u16* __restrict__ Oout)
{
  __shared__ char lds[65536];
  char* Ks = lds;            // [128][64] bf16, swizzled (16KB)
  char* Vs = lds + 16384;    // [64][128] bf16, swizzled (16KB) = V^T tile
  char* Ps = lds + 32768;    // [128][128] bf16, swizzled (32KB)
  const int t = threadIdx.x;
  const int lane = t & 63, w = t >> 6;
  const int lr = lane & 15, lg = lane >> 4;
  const int qt = blockIdx.x & 7, bh = blockIdx.x >> 3;
  const int b = bh >> 4, h = bh & 15;
  const int q0 = qt << 7;
  const u32 fmt = *fmtp;
  const u8* mB = (const u8*)maskp;
  const u32* mW = (const u32*)maskp;

  // stage Q tile into Ps area temporarily ([128][64] swizzled), pull frags to regs
  #pragma unroll
  for (int j = 0; j < 4; ++j) {
    int f = j * 256 + t, r = f >> 3, c = f & 7;
    u32x4 v = *(const u32x4*)(qh + ((size_t)bh * 1024 + q0 + r) * 64 + c * 8);
    *(u32x4*)(Ps + r * 128 + ((c ^ (r & 7)) << 4)) = v;
  }
  __syncthreads();
  bf16x8 aq[2][2];
  #pragma unroll
  for (int mf = 0; mf < 2; ++mf)
    #pragma unroll
    for (int ks = 0; ks < 2; ++ks) {
      int row = w * 32 + mf * 16 + lr;
      aq[mf][ks] = *(const bf16x8*)(Ps + row * 128 + (((ks * 4 + lg) ^ (row & 7)) << 4));
    }

  float mrun[2][4], lrun[2][4];
  #pragma unroll
  for (int mf = 0; mf < 2; ++mf)
    #pragma unroll
    for (int i = 0; i < 4; ++i) { mrun[mf][i] = -3e38f; lrun[mf][i] = 0.f; }

  // ---- pass 1: softmax stats ----
  for (int kt = 0; kt < 8; ++kt) {
    __syncthreads();
    #pragma unroll
    for (int j = 0; j < 4; ++j) {
      int f = j * 256 + t, r = f >> 3, c = f & 7;
      u32x4 v = *(const u32x4*)(khp + ((size_t)bh * 1024 + kt * 128 + r) * 64 + c * 8);
      *(u32x4*)(Ks + r * 128 + ((c ^ (r & 7)) << 4)) = v;
    }
    __syncthreads();
    f32x4 s[2][8];
    #pragma unroll
    for (int nf = 0; nf < 8; ++nf) {
      int row = nf * 16 + lr;
      bf16x8 b0 = *(const bf16x8*)(Ks + row * 128 + ((lg ^ (row & 7)) << 4));
      bf16x8 b1 = *(const bf16x8*)(Ks + row * 128 + (((4 + lg) ^ (row & 7)) << 4));
      #pragma unroll
      for (int mf = 0; mf < 2; ++mf) {
        f32x4 z = {};
        z = __builtin_amdgcn_mfma_f32_16x16x32_bf16(aq[mf][0], b0, z, 0, 0, 0);
        z = __builtin_amdgcn_mfma_f32_16x16x32_bf16(aq[mf][1], b1, z, 0, 0, 0);
        s[mf][nf] = z;
      }
    }
    #pragma unroll
    for (int mf = 0; mf < 2; ++mf)
      #pragma unroll
      for (int i = 0; i < 4; ++i) {
        int qg = q0 + w * 32 + mf * 16 + lg * 4 + i;
        size_t mb = ((size_t)b * 1024 + qg) * 1024 + (size_t)kt * 128 + lr;
        float vv[8], rmax = -3e38f;
        #pragma unroll
        for (int nf = 0; nf < 8; ++nf) {
          float x = s[mf][nf][i] * 0.125f;
          u32 mk = fmt ? (u32)(mW[mb + nf * 16] != 0) : (u32)(mB[mb + nf * 16] != 0);
          x = mk ? -1e9f : x;
          vv[nf] = x;
          rmax = fmaxf(rmax, x);
        }
        rmax = fmaxf(rmax, __shfl_xor(rmax, 1));
        rmax = fmaxf(rmax, __shfl_xor(rmax, 2));
        rmax = fmaxf(rmax, __shfl_xor(rmax, 4));
        rmax = fmaxf(rmax, __shfl_xor(rmax, 8));
        float mnew = fmaxf(mrun[mf][i], rmax);
        float ps = 0.f;
        #pragma unroll
        for (int nf = 0; nf < 8; ++nf) ps += __expf(vv[nf] - mnew);
        ps += __shfl_xor(ps, 1);
        ps += __shfl_xor(ps, 2);
        ps += __shfl_xor(ps, 4);
        ps += __shfl_xor(ps, 8);
        lrun[mf][i] = lrun[mf][i] * __expf(mrun[mf][i] - mnew) + ps;
        mrun[mf][i] = mnew;
      }
  }

  // ---- pass 2: write P, accumulate O ----
  f32x4 oacc[2][4] = {};
  for (int kt = 0; kt < 8; ++kt) {
    __syncthreads();
    #pragma unroll
    for (int j = 0; j < 4; ++j) {
      int f = j * 256 + t, r = f >> 3, c = f & 7;
      u32x4 v = *(const u32x4*)(khp + ((size_t)bh * 1024 + kt * 128 + r) * 64 + c * 8);
      *(u32x4*)(Ks + r * 128 + ((c ^ (r & 7)) << 4)) = v;
    }
    #pragma unroll
    for (int j = 0; j < 4; ++j) {
      int f = j * 256 + t, r = f >> 4, c = f & 15;
      u32x4 v = *(const u32x4*)(vt + ((size_t)bh * 64 + r) * 1024 + (size_t)kt * 128 + c * 8);
      *(u32x4*)(Vs + r * 256 + ((c ^ (r & 15)) << 4)) = v;
    }
    __syncthreads();
    f32x4 s[2][8];
    #pragma unroll
    for (int nf = 0; nf < 8; ++nf) {
      int row = nf * 16 + lr;
      bf16x8 b0 = *(const bf16x8*)(Ks + row * 128 + ((lg ^ (row & 7)) << 4));
      bf16x8 b1 = *(const bf16x8*)(Ks + row * 128 + (((4 + lg) ^ (row & 7)) << 4));
      #pragma unroll
      for (int mf = 0; mf < 2; ++mf) {
        f32x4 z = {};
        z = __builtin_amdgcn_mfma_f32_16x16x32_bf16(aq[mf][0], b0, z, 0, 0, 0);
        z = __builtin_amdgcn_mfma_f32_16x16x32_bf16(aq[mf][1], b1, z, 0, 0, 0);
        s[mf][nf] = z;
      }
    }
    #pragma unroll
    for (int mf = 0; mf < 2; ++mf)
      #pragma unroll
      for (int i = 0; i < 4; ++i) {
        int qg = q0 + w * 32 + mf * 16 + lg * 4 + i;
        int ql = w * 32 + mf * 16 + lg * 4 + i;
        size_t mb = ((size_t)b * 1024 + qg) * 1024 + (size_t)kt * 128 + lr;
        float rm = mrun[mf][i];
        float rl = 1.0f / lrun[mf][i];
        size_t ob = ((size_t)bh * 1024 + qg) * 1024 + (size_t)kt * 128 + lr;
        #pragma unroll
        for (int nf = 0; nf < 8; ++nf) {
          float x = s[mf][nf][i] * 0.125f;
          u32 mk = fmt ? (u32)(mW[mb + nf * 16] != 0) : (u32)(mB[mb + nf * 16] != 0);
          x = mk ? -1e9f : x;
          float p = __expf(x - rm) * rl;
          attn_out[ob + nf * 16] = p;
          int kl = nf * 16 + lr;
          *(u16*)(Ps + ql * 256 + (((kl >> 3) ^ (ql & 15)) << 4) + ((kl & 7) << 1)) = f2bf(p);
        }
      }
    asm volatile("s_waitcnt lgkmcnt(0)" ::: "memory");  // P writes -> P reads (wave-local band)
    #pragma unroll
    for (int kk = 0; kk < 4; ++kk) {
      bf16x8 pa[2], bv[4];
      #pragma unroll
      for (int mf = 0; mf < 2; ++mf) {
        int row = w * 32 + mf * 16 + lr;
        pa[mf] = *(const bf16x8*)(Ps + row * 256 + (((kk * 4 + lg) ^ (row & 15)) << 4));
      }
      #pragma unroll
      for (int nd = 0; nd < 4; ++nd) {
        int row = nd * 16 + lr;
        bv[nd] = *(const bf16x8*)(Vs + row * 256 + (((kk * 4 + lg) ^ (row & 15)) << 4));
      }
      #pragma unroll
      for (int mf = 0; mf < 2; ++mf)
        #pragma unroll
        for (int nd = 0; nd < 4; ++nd)
          oacc[mf][nd] = __builtin_amdgcn_mfma_f32_16x16x32_bf16(pa[mf], bv[nd], oacc[mf][nd], 0, 0, 0);
    }
  }

  #pragma unroll
  for (int mf = 0; mf < 2; ++mf)
    #pragma unroll
    for (int nd = 0; nd < 4; ++nd)
      #pragma unroll
      for (int i = 0; i < 4; ++i) {
        int qg = q0 + w * 32 + mf * 16 + lg * 4 + i;
        int d = nd * 16 + lr;
        Oout[((size_t)b * 1024 + qg) * 1024 + h * 64 + d] = f2bf(oacc[mf][nd][i]);
      }
}

// ---------------- in-place LayerNorm over D=1024 ----------------
__global__ __launch_bounds__(256) void ln_kernel(
    float* __restrict__ x, const float* __restrict__ gam, const float* __restrict__ bet)
{
  const int row = blockIdx.x, t = threadIdx.x;
  const int w = t >> 6, lane = t & 63;
  float4 v = *(const float4*)(x + (size_t)row * 1024 + t * 4);
  float s1 = v.x + v.y + v.z + v.w;
  float s2 = v.x * v.x + v.y * v.y + v.z * v.z + v.w * v.w;
  #pragma unroll
  for (int d = 1; d < 64; d <<= 1) { s1 += __shfl_xor(s1, d); s2 += __shfl_xor(s2, d); }
  __shared__ float red[8];
  if (lane == 0) { red[w] = s1; red[4 + w] = s2; }
  __syncthreads();
  s1 = red[0] + red[1] + red[2] + red[3];
  s2 = red[4] + red[5] + red[6] + red[7];
  const float mu = s1 * (1.f / 1024.f);
  const float var = s2 * (1.f / 1024.f) - mu * mu;
  const float rs = rsqrtf(var + 1e-5f);
  float4 g4 = *(const float4*)(gam + t * 4);
  float4 b4 = *(const float4*)(bet + t * 4);
  v.x = (v.x - mu) * rs * g4.x + b4.x;
  v.y = (v.y - mu) * rs * g4.y + b4.y;
  v.z = (v.z - mu) * rs * g4.z + b4.z;
  v.w = (v.w - mu) * rs * g4.w + b4.w;
  *(float4*)(x + (size_t)row * 1024 + t * 4) = v;
}

extern "C" void kernel_launch(void* const* d_in, const int* in_sizes, int n_in,
                              void* d_out, int out_size, void* d_ws, size_t ws_size,
                              hipStream_t stream) {
  const float* q   = (const float*)d_in[0];
  const float* k   = (const float*)d_in[1];
  const float* v   = (const float*)d_in[2];
  const void*  msk = d_in[3];
  const float* wq  = (const float*)d_in[4];
  const float* bq  = (const float*)d_in[5];
  const float* wk  = (const float*)d_in[6];
  const float* bk  = (const float*)d_in[7];
  const float* wv  = (const float*)d_in[8];
  const float* bv  = (const float*)d_in[9];
  const float* wes = (const float*)d_in[10];
  const float* fcw = (const float*)d_in[11];
  const float* fcb = (const float*)d_in[12];
  const float* lng = (const float*)d_in[13];
  const float* lnb = (const float*)d_in[14];

  u16* qh   = (u16*)d_ws;
  u16* khp  = qh  + (size_t)8388608;
  u16* vt   = khp + (size_t)8388608;
  u16* Obuf = vt  + (size_t)8388608;
  u32* flag = (u32*)((char*)d_ws + (size_t)4 * 16777216);

  float* outp     = (float*)d_out;
  float* attn_out = outp + (size_t)8388608;

  probe_mask<<<1, 256, 0, stream>>>((const u32*)msk, flag);
  gemm_bt<0><<<512, 256, 0, stream>>>(q, nullptr, wq, bq, nullptr, nullptr, qh, nullptr);
  gemm_bt<1><<<512, 256, 0, stream>>>(k, nullptr, wk, bk, wes, nullptr, khp, nullptr);
  gemm_bt<2><<<512, 256, 0, stream>>>(v, nullptr, wv, bv, nullptr, nullptr, vt, nullptr);
  attn_kernel<<<1024, 256, 0, stream>>>(qh, khp, vt, msk, flag, attn_out, Obuf);
  gemm_bt<3><<<512, 256, 0, stream>>>(nullptr, Obuf, fcw, fcb, nullptr, q, nullptr, outp);
  ln_kernel<<<8192, 256, 0, stream>>>(outp, lng, lnb);
}